// Round 1
// baseline (904.351 us; speedup 1.0000x reference)
//
#include <hip/hip_runtime.h>

// Problem constants
#define N_ROWS 65536   // 32*2048 rows
#define DDIM   64
#define KCODES 2048
#define NB     128     // rows per block
#define KC     128     // codes per LDS chunk
#define TAU    0.05f   // fp32 top-2 gap threshold for fp64 refinement

// d_out layout (float32, concatenated in reference return order)
#define Q_OFF    ((size_t)0)
#define ENC_OFF  ((size_t)N_ROWS * DDIM)                 // 4194304
#define IDX_OFF  (ENC_OFF + (size_t)N_ROWS * KCODES)     // 138412032
#define LOSS_OFF (IDX_OFF + (size_t)N_ROWS)              // 138477568

#define INV_ND (1.0f / ((float)N_ROWS * (float)DDIM))

// d_ws layout: [0,2048) float esq ; [2048, 2048+65536) int flags  (~270 KB)

__global__ void vq_prep(const float* __restrict__ emb, float* __restrict__ esq,
                        float* __restrict__ out) {
    int k = blockIdx.x * 256 + threadIdx.x;
    float s = 0.f;
    #pragma unroll 8
    for (int d = 0; d < DDIM; ++d) { float e = emb[(size_t)d * KCODES + k]; s += e * e; }
    esq[k] = s;
    if (k == 0) out[LOSS_OFF] = 0.f;   // loss accumulator (d_out is poisoned each launch)
}

__launch_bounds__(256, 2)
__global__ void vq_main(const float* __restrict__ x, const float* __restrict__ emb,
                        const float* __restrict__ esq, int* __restrict__ flags,
                        float* __restrict__ out) {
    // LDS: exactly 64 KB. Xs = X-tile transposed [64][128]; Es = E-chunk [64][128].
    // After the K-loop, the Xs region is reused for the argmin reduction.
    __shared__ __align__(16) float smem[16384];
    float* Xs = smem;
    float* Es = smem + DDIM * NB;

    const int tid = threadIdx.x;
    const int tx  = tid & 15;   // code group (16 groups of 8 codes)
    const int ty  = tid >> 4;   // row group  (16 groups of 8 rows)
    const int r0  = blockIdx.x * NB;

    // Stage X transposed: Xs[d][row]
    for (int i = tid; i < NB * (DDIM / 4); i += 256) {
        int row = i >> 4;
        int d4  = (i & 15) << 2;
        float4 v = *(const float4*)(x + (size_t)(r0 + row) * DDIM + d4);
        Xs[(d4 + 0) * NB + row] = v.x;
        Xs[(d4 + 1) * NB + row] = v.y;
        Xs[(d4 + 2) * NB + row] = v.z;
        Xs[(d4 + 3) * NB + row] = v.w;
    }

    float m1[8], m2[8];
    int   i1[8];
    #pragma unroll
    for (int r = 0; r < 8; ++r) { m1[r] = 3.4e38f; m2[r] = 3.4e38f; i1[r] = 0; }

    for (int kc = 0; kc < KCODES; kc += KC) {
        __syncthreads();   // previous chunk's readers done (also drains prior stores)
        // Stage embeddings chunk Es[d][c] (already [d][k] in global, no transpose)
        for (int i = tid; i < DDIM * (KC / 4); i += 256) {
            int d  = i >> 5;
            int c4 = (i & 31) << 2;
            *(float4*)(Es + d * KC + c4) =
                *(const float4*)(emb + (size_t)d * KCODES + kc + c4);
        }
        __syncthreads();

        // Prefetch ||e||^2 for this thread's 8 codes (L2-hot, consumed after d-loop)
        float4 e0 = *(const float4*)(esq + kc + tx * 8);
        float4 e1 = *(const float4*)(esq + kc + tx * 8 + 4);

        // Issue this chunk's share of encodings ZERO stores (fire-and-forget).
        // They drain during the 4096 FMAs below; the next barrier's vmcnt(0)
        // guarantees ordering vs. the final 1.0 write.
        {
            int ci5 = (kc >> 7) << 5;  // base float4-column of this chunk
            float4 z = make_float4(0.f, 0.f, 0.f, 0.f);
            #pragma unroll
            for (int j = 0; j < 16; ++j) {
                int s   = tid + (j << 8);          // 0..4095
                int row = s >> 5;                  // 32 float4 per row per chunk
                int c4  = s & 31;
                *(float4*)(out + ENC_OFF + (size_t)(r0 + row) * KCODES
                           + (size_t)((ci5 + c4) << 2)) = z;
            }
        }

        // 8x8 register-tile fp32 GEMM over this chunk
        float acc[8][8];
        #pragma unroll
        for (int r = 0; r < 8; ++r)
            #pragma unroll
            for (int c = 0; c < 8; ++c) acc[r][c] = 0.f;

        #pragma unroll 2
        for (int d = 0; d < DDIM; ++d) {
            float4 a0 = *(const float4*)(Xs + d * NB + ty * 8);
            float4 a1 = *(const float4*)(Xs + d * NB + ty * 8 + 4);
            float4 b0 = *(const float4*)(Es + d * KC + tx * 8);
            float4 b1 = *(const float4*)(Es + d * KC + tx * 8 + 4);
            float a[8] = {a0.x, a0.y, a0.z, a0.w, a1.x, a1.y, a1.z, a1.w};
            float b[8] = {b0.x, b0.y, b0.z, b0.w, b1.x, b1.y, b1.z, b1.w};
            #pragma unroll
            for (int r = 0; r < 8; ++r)
                #pragma unroll
                for (int c = 0; c < 8; ++c)
                    acc[r][c] = fmaf(a[r], b[c], acc[r][c]);
        }

        // Fold into per-row top-2 (dist = ||e||^2 - 2*sim ; ||x||^2 is constant per row)
        float eq[8] = {e0.x, e0.y, e0.z, e0.w, e1.x, e1.y, e1.z, e1.w};
        #pragma unroll
        for (int c = 0; c < 8; ++c) {
            int k = kc + tx * 8 + c;
            #pragma unroll
            for (int r = 0; r < 8; ++r) {
                float dist = fmaf(-2.f, acc[r][c], eq[c]);
                if (dist < m1[r]) { m2[r] = m1[r]; m1[r] = dist; i1[r] = k; }
                else if (dist < m2[r]) m2[r] = dist;
            }
        }
    }

    __syncthreads();   // drains last zero-stores; Xs region now dead -> reuse
    float* red  = smem;                      // [128][16][3]: m1, idx, m2
    int*   indS = (int*)(smem + 6144);       // [128]
    float* lred = smem + 6144 + 128;         // [4]

    #pragma unroll
    for (int r = 0; r < 8; ++r) {
        int row = ty * 8 + r;
        float* p = red + (size_t)(row * 16 + tx) * 3;
        p[0] = m1[r];
        p[1] = (float)i1[r];
        p[2] = m2[r];
    }
    __syncthreads();

    // Per-row scan across the 16 code-groups: global top-2 + index (low-idx tiebreak,
    // matching argmax-first semantics)
    if (tid < NB) {
        int row = tid;
        const float* p = red + (size_t)row * 48;
        float gm1 = 3.4e38f; int gi1 = 0x7fffffff; int wt = -1;
        for (int t = 0; t < 16; ++t) {
            float v  = p[t * 3 + 0];
            int   iv = (int)p[t * 3 + 1];
            if (v < gm1 || (v == gm1 && iv < gi1)) { gm1 = v; gi1 = iv; wt = t; }
        }
        float gm2 = 3.4e38f;
        for (int t = 0; t < 16; ++t) {
            float cand = (t == wt) ? p[t * 3 + 2] : p[t * 3 + 0];
            gm2 = fminf(gm2, cand);
        }
        int gr = r0 + row;
        out[IDX_OFF + gr] = (float)gi1;
        flags[gr] = (gm2 - gm1 < TAU) ? 1 : 0;   // near-tie -> fp64 refinement
        indS[row] = gi1;
        out[ENC_OFF + (size_t)gr * KCODES + gi1] = 1.0f;  // after zero-drain barrier
    }
    __syncthreads();

    // Quantized rows + commitment-loss partial
    float lpart = 0.f;
    for (int i = tid; i < NB * (DDIM / 4); i += 256) {
        int row = i >> 4;
        int d4  = (i & 15) << 2;
        int idx = indS[row];
        int gr  = r0 + row;
        float4 q;
        q.x = emb[(size_t)(d4 + 0) * KCODES + idx];
        q.y = emb[(size_t)(d4 + 1) * KCODES + idx];
        q.z = emb[(size_t)(d4 + 2) * KCODES + idx];
        q.w = emb[(size_t)(d4 + 3) * KCODES + idx];
        *(float4*)(out + Q_OFF + (size_t)gr * DDIM + d4) = q;
        float4 xv = *(const float4*)(x + (size_t)gr * DDIM + d4);
        float dx = q.x - xv.x, dy = q.y - xv.y, dz = q.z - xv.z, dw = q.w - xv.w;
        lpart += dx * dx + dy * dy + dz * dz + dw * dw;
    }
    #pragma unroll
    for (int o = 32; o > 0; o >>= 1) lpart += __shfl_down(lpart, o);
    if ((tid & 63) == 0) lred[tid >> 6] = lpart;
    __syncthreads();
    if (tid == 0)
        atomicAdd(out + LOSS_OFF, (lred[0] + lred[1] + lred[2] + lred[3]) * INV_ND);
}

// Exact fp64 argmin for rows whose fp32 top-2 gap was below TAU (~0.5% of rows).
__global__ void vq_refine(const float* __restrict__ x, const float* __restrict__ emb,
                          const int* __restrict__ flags, float* __restrict__ out) {
    const int lane = threadIdx.x & 63;
    const int wid  = threadIdx.x >> 6;
    for (int rr = 0; rr < 8; ++rr) {
        int row = (blockIdx.x * 4 + wid) * 8 + rr;
        if (flags[row] == 0) continue;                 // wave-uniform
        const float* xr = x + (size_t)row * DDIM;
        double best = 1e300; int bidx = 0x7fffffff;
        for (int k = lane; k < KCODES; k += 64) {
            double s = 0.0, ee = 0.0;
            for (int d = 0; d < DDIM; ++d) {
                double e = (double)emb[(size_t)d * KCODES + k];
                s  = fma((double)xr[d], e, s);
                ee = fma(e, e, ee);
            }
            double dist = ee - 2.0 * s;
            if (dist < best) { best = dist; bidx = k; }  // within-lane k ascending
        }
        #pragma unroll
        for (int o = 32; o > 0; o >>= 1) {
            double ob = __shfl_down(best, o);
            int    oi = __shfl_down(bidx, o);
            if (ob < best || (ob == best && oi < bidx)) { best = ob; bidx = oi; }
        }
        bidx = __shfl(bidx, 0);
        int oldIdx = (int)out[IDX_OFF + row];
        if (bidx == oldIdx) continue;                  // uniform after broadcast
        if (lane == 0) {
            out[IDX_OFF + row] = (float)bidx;
            out[ENC_OFF + (size_t)row * KCODES + oldIdx] = 0.f;
            out[ENC_OFF + (size_t)row * KCODES + bidx]   = 1.f;
        }
        float eN = emb[(size_t)lane * KCODES + bidx];
        float eO = emb[(size_t)lane * KCODES + oldIdx];
        float xv = xr[lane];
        out[Q_OFF + (size_t)row * DDIM + lane] = eN;
        float dn = eN - xv, dod = eO - xv;
        float delta = dn * dn - dod * dod;
        #pragma unroll
        for (int o = 32; o > 0; o >>= 1) delta += __shfl_down(delta, o);
        if (lane == 0) atomicAdd(out + LOSS_OFF, delta * INV_ND);
    }
}

extern "C" void kernel_launch(void* const* d_in, const int* in_sizes, int n_in,
                              void* d_out, int out_size, void* d_ws, size_t ws_size,
                              hipStream_t stream) {
    const float* x   = (const float*)d_in[0];   // [65536, 64]
    const float* emb = (const float*)d_in[1];   // [64, 2048]
    float* out   = (float*)d_out;
    float* esq   = (float*)d_ws;                // [2048]
    int*   flags = (int*)d_ws + KCODES;         // [65536]
    hipLaunchKernelGGL(vq_prep,   dim3(KCODES / 256), dim3(256), 0, stream, emb, esq, out);
    hipLaunchKernelGGL(vq_main,   dim3(N_ROWS / NB),  dim3(256), 0, stream, x, emb, esq, flags, out);
    hipLaunchKernelGGL(vq_refine, dim3(N_ROWS / 32),  dim3(256), 0, stream, x, emb, flags, out);
}

// Round 2
// 759.166 us; speedup vs baseline: 1.1912x; 1.1912x over previous
//
#include <hip/hip_runtime.h>

// Problem constants
#define N_ROWS 65536   // 32*2048 rows
#define DDIM   64
#define KCODES 2048
#define NB     128     // rows per block
#define CHUNK  256     // codes per LDS chunk
#define NCHUNK (KCODES / CHUNK)
#define TAU    0.05f   // top-2 gap threshold for fp64 refinement

// d_out layout (float32, concatenated in reference return order)
#define Q_OFF    ((size_t)0)
#define ENC_OFF  ((size_t)N_ROWS * DDIM)                 // 4194304
#define IDX_OFF  (ENC_OFF + (size_t)N_ROWS * KCODES)     // 138412032
#define LOSS_OFF (IDX_OFF + (size_t)N_ROWS)              // 138477568
#define INV_ND (1.0f / ((float)N_ROWS * (float)DDIM))

// d_ws layout (bytes):
//   [0, 524288)        : bf16 B image, 8 chunks x { hi[256][64], lo[256][64] } shorts
//                        (k index stored XOR-swizzled: kk = k ^ ((code&7)<<3))
//   [524288, 532480)   : esq, 2048 floats
//   [532480, 794624)   : flags, 65536 ints
#define WS_ESQ_OFF   (524288)
#define WS_FLAGS_OFF (532480)

typedef __attribute__((ext_vector_type(8))) short short8;
typedef __attribute__((ext_vector_type(4))) float f32x4;

__device__ __forceinline__ unsigned short f2bf(float f) {
    unsigned u = __float_as_uint(f);
    u += 0x7FFFu + ((u >> 16) & 1u);
    return (unsigned short)(u >> 16);
}
__device__ __forceinline__ float bf2f(unsigned short h) {
    return __uint_as_float(((unsigned)h) << 16);
}

// Split embeddings into bf16 hi/lo (swizzled layout) + ||e||^2 + zero loss slot.
__global__ void vq_prep(const float* __restrict__ emb, char* __restrict__ ws,
                        float* __restrict__ out) {
    int t = blockIdx.x * 256 + threadIdx.x;        // [0, 131072)
    int code = t & (KCODES - 1);
    int d    = t >> 11;
    float v = emb[(size_t)d * KCODES + code];
    unsigned short hi = f2bf(v);
    unsigned short lo = f2bf(v - bf2f(hi));
    int ch = code >> 8;
    int lc = code & 255;
    int kk = d ^ ((code & 7) << 3);
    short* base = (short*)ws + (size_t)ch * 32768 + lc * 64 + kk;
    base[0]     = (short)hi;
    base[16384] = (short)lo;
    if (t < KCODES) {
        float s = 0.f;
        for (int dd = 0; dd < DDIM; ++dd) {
            float e = emb[(size_t)dd * KCODES + t];
            s += e * e;
        }
        ((float*)(ws + WS_ESQ_OFF))[t] = s;
    }
    if (t == 0) out[LOSS_OFF] = 0.f;
}

__launch_bounds__(256, 2)
__global__ void vq_main(const float* __restrict__ x, const float* __restrict__ emb,
                        const char* __restrict__ ws, int* __restrict__ flags,
                        float* __restrict__ out) {
    __shared__ __align__(16) short Bs[32768];   // 64 KB: hi[256][64] then lo[256][64]
    const int tid = threadIdx.x;
    const int l = tid & 63, w = tid >> 6;
    const int q = l >> 4, c = l & 15;
    const int r0 = blockIdx.x * NB;
    const float* esq = (const float*)(ws + WS_ESQ_OFF);

    // A fragments: this wave's 32 rows, bf16 hi/lo, resident in registers.
    // A-operand layout: lane holds A[m = l&15][k = q*8 + j].
    short8 ah0[2], ah1[2], al0[2], al1[2];
    #pragma unroll
    for (int rt = 0; rt < 2; ++rt) {
        int row = r0 + w * 32 + rt * 16 + c;
        const float4* xr = (const float4*)(x + (size_t)row * DDIM);
        float4 f0 = xr[q * 2],     f1 = xr[q * 2 + 1];
        float4 f2 = xr[8 + q * 2], f3 = xr[8 + q * 2 + 1];
        float a0[8] = {f0.x,f0.y,f0.z,f0.w,f1.x,f1.y,f1.z,f1.w};
        float a1[8] = {f2.x,f2.y,f2.z,f2.w,f3.x,f3.y,f3.z,f3.w};
        #pragma unroll
        for (int j = 0; j < 8; ++j) {
            unsigned short h0 = f2bf(a0[j]);
            ah0[rt][j] = (short)h0;
            al0[rt][j] = (short)f2bf(a0[j] - bf2f(h0));
            unsigned short h1 = f2bf(a1[j]);
            ah1[rt][j] = (short)h1;
            al1[rt][j] = (short)f2bf(a1[j] - bf2f(h1));
        }
    }

    float m1[8], m2[8]; int i1[8];
    #pragma unroll
    for (int s = 0; s < 8; ++s) { m1[s] = 3.4e38f; m2[s] = 3.4e38f; i1[s] = 0; }

    for (int ch = 0; ch < NCHUNK; ++ch) {
        const int kc = ch * CHUNK;
        __syncthreads();   // readers of previous chunk done; prior stores drained
        // Stage 64 KB bf16 chunk from ws (linear, conflict-free)
        {
            const int4* g4 = (const int4*)(ws + (size_t)ch * 65536);
            int4* s4 = (int4*)Bs;
            #pragma unroll
            for (int i = 0; i < 16; ++i) s4[i * 256 + tid] = g4[i * 256 + tid];
        }
        __syncthreads();

        // Fire-and-forget zero-stores for this chunk's one-hot slab (128 rows x 256 codes).
        // They drain under the MFMA work; next barrier's vmcnt(0) orders them
        // before the final 1.0 write.
        {
            float4 z = make_float4(0.f, 0.f, 0.f, 0.f);
            float* ebase = out + ENC_OFF + (size_t)r0 * KCODES + kc;
            #pragma unroll
            for (int j = 0; j < 32; ++j) {
                int s   = j * 256 + tid;
                int row = s >> 6;
                int c4  = s & 63;
                *(float4*)(ebase + (size_t)row * KCODES + (c4 << 2)) = z;
            }
        }

        // 16 code-tiles of 16; 3-term bf16-split MFMA (hi*hi + hi*lo + lo*hi)
        const int swz = (c & 7) << 3;
        for (int t = 0; t < 16; ++t) {
            int codeL = t * 16 + c;
            const short* ph = Bs + codeL * 64;
            const short* pl = ph + 16384;
            int k0 = (q * 8) ^ swz;
            int k1 = (32 + q * 8) ^ swz;
            short8 bh0 = *(const short8*)(ph + k0);
            short8 bh1 = *(const short8*)(ph + k1);
            short8 bl0 = *(const short8*)(pl + k0);
            short8 bl1 = *(const short8*)(pl + k1);
            int   kidx = kc + t * 16 + c;
            float eq   = esq[kidx];
            #pragma unroll
            for (int rt = 0; rt < 2; ++rt) {
                f32x4 acc = {0.f, 0.f, 0.f, 0.f};
                acc = __builtin_amdgcn_mfma_f32_16x16x32_bf16(ah0[rt], bh0, acc, 0, 0, 0);
                acc = __builtin_amdgcn_mfma_f32_16x16x32_bf16(ah1[rt], bh1, acc, 0, 0, 0);
                acc = __builtin_amdgcn_mfma_f32_16x16x32_bf16(ah0[rt], bl0, acc, 0, 0, 0);
                acc = __builtin_amdgcn_mfma_f32_16x16x32_bf16(ah1[rt], bl1, acc, 0, 0, 0);
                acc = __builtin_amdgcn_mfma_f32_16x16x32_bf16(al0[rt], bh0, acc, 0, 0, 0);
                acc = __builtin_amdgcn_mfma_f32_16x16x32_bf16(al1[rt], bh1, acc, 0, 0, 0);
                #pragma unroll
                for (int g = 0; g < 4; ++g) {
                    float dist = fmaf(-2.f, acc[g], eq);   // + ||x||^2 omitted (row-const)
                    int s = rt * 4 + g;
                    bool better = dist < m1[s];
                    m2[s] = fminf(m2[s], fmaxf(m1[s], dist));
                    m1[s] = fminf(m1[s], dist);
                    i1[s] = better ? kidx : i1[s];
                }
            }
        }
    }

    __syncthreads();   // drains last zero-stores; Bs now dead -> reuse for reduction
    float* red  = (float*)Bs;                 // [128 rows][16 cols][3]: m1, idx, m2
    int*   indS = (int*)(red + 6144);         // [128]
    float* lred = red + 6144 + 128;           // [4]

    // C/D layout: col = l&15, row = q*4 + reg  [m89]
    #pragma unroll
    for (int rt = 0; rt < 2; ++rt)
        #pragma unroll
        for (int g = 0; g < 4; ++g) {
            int lrow = w * 32 + rt * 16 + q * 4 + g;
            float* p = red + (size_t)(lrow * 16 + c) * 3;
            p[0] = m1[rt * 4 + g];
            p[1] = (float)i1[rt * 4 + g];
            p[2] = m2[rt * 4 + g];
        }
    __syncthreads();

    // Per-row scan across the 16 col-lanes: global top-2 + index (low-idx tiebreak)
    if (tid < NB) {
        int row = tid;
        const float* p = red + (size_t)row * 48;
        float gm1 = 3.4e38f; int gi1 = 0x7fffffff; int wt = -1;
        for (int t = 0; t < 16; ++t) {
            float v  = p[t * 3 + 0];
            int   iv = (int)p[t * 3 + 1];
            if (v < gm1 || (v == gm1 && iv < gi1)) { gm1 = v; gi1 = iv; wt = t; }
        }
        float gm2 = 3.4e38f;
        for (int t = 0; t < 16; ++t) {
            float cand = (t == wt) ? p[t * 3 + 2] : p[t * 3 + 0];
            gm2 = fminf(gm2, cand);
        }
        int gr = r0 + row;
        out[IDX_OFF + gr] = (float)gi1;
        flags[gr] = (gm2 - gm1 < TAU) ? 1 : 0;
        indS[row] = gi1;
        out[ENC_OFF + (size_t)gr * KCODES + gi1] = 1.0f;  // after zero-drain barrier
    }
    __syncthreads();

    // Quantized rows + commitment-loss partial (exact fp32 inputs)
    float lpart = 0.f;
    for (int i = tid; i < NB * (DDIM / 4); i += 256) {
        int row = i >> 4;
        int d4  = (i & 15) << 2;
        int idx = indS[row];
        int gr  = r0 + row;
        float4 qv;
        qv.x = emb[(size_t)(d4 + 0) * KCODES + idx];
        qv.y = emb[(size_t)(d4 + 1) * KCODES + idx];
        qv.z = emb[(size_t)(d4 + 2) * KCODES + idx];
        qv.w = emb[(size_t)(d4 + 3) * KCODES + idx];
        *(float4*)(out + Q_OFF + (size_t)gr * DDIM + d4) = qv;
        float4 xv = *(const float4*)(x + (size_t)gr * DDIM + d4);
        float dx = qv.x - xv.x, dy = qv.y - xv.y, dz = qv.z - xv.z, dw = qv.w - xv.w;
        lpart += dx * dx + dy * dy + dz * dz + dw * dw;
    }
    #pragma unroll
    for (int o = 32; o > 0; o >>= 1) lpart += __shfl_down(lpart, o);
    if ((tid & 63) == 0) lred[tid >> 6] = lpart;
    __syncthreads();
    if (tid == 0)
        atomicAdd(out + LOSS_OFF, (lred[0] + lred[1] + lred[2] + lred[3]) * INV_ND);
}

// Exact fp64 argmin for rows whose top-2 gap was below TAU.
__global__ void vq_refine(const float* __restrict__ x, const float* __restrict__ emb,
                          const int* __restrict__ flags, float* __restrict__ out) {
    const int lane = threadIdx.x & 63;
    const int wid  = threadIdx.x >> 6;
    for (int rr = 0; rr < 8; ++rr) {
        int row = (blockIdx.x * 4 + wid) * 8 + rr;
        if (flags[row] == 0) continue;                 // wave-uniform
        const float* xr = x + (size_t)row * DDIM;
        double best = 1e300; int bidx = 0x7fffffff;
        for (int k = lane; k < KCODES; k += 64) {
            double s = 0.0, ee = 0.0;
            for (int d = 0; d < DDIM; ++d) {
                double e = (double)emb[(size_t)d * KCODES + k];
                s  = fma((double)xr[d], e, s);
                ee = fma(e, e, ee);
            }
            double dist = ee - 2.0 * s;
            if (dist < best) { best = dist; bidx = k; }
        }
        #pragma unroll
        for (int o = 32; o > 0; o >>= 1) {
            double ob = __shfl_down(best, o);
            int    oi = __shfl_down(bidx, o);
            if (ob < best || (ob == best && oi < bidx)) { best = ob; bidx = oi; }
        }
        bidx = __shfl(bidx, 0);
        int oldIdx = (int)out[IDX_OFF + row];
        if (bidx == oldIdx) continue;
        if (lane == 0) {
            out[IDX_OFF + row] = (float)bidx;
            out[ENC_OFF + (size_t)row * KCODES + oldIdx] = 0.f;
            out[ENC_OFF + (size_t)row * KCODES + bidx]   = 1.f;
        }
        float eN = emb[(size_t)lane * KCODES + bidx];
        float eO = emb[(size_t)lane * KCODES + oldIdx];
        float xv = xr[lane];
        out[Q_OFF + (size_t)row * DDIM + lane] = eN;
        float dn = eN - xv, dod = eO - xv;
        float delta = dn * dn - dod * dod;
        #pragma unroll
        for (int o = 32; o > 0; o >>= 1) delta += __shfl_down(delta, o);
        if (lane == 0) atomicAdd(out + LOSS_OFF, delta * INV_ND);
    }
}

extern "C" void kernel_launch(void* const* d_in, const int* in_sizes, int n_in,
                              void* d_out, int out_size, void* d_ws, size_t ws_size,
                              hipStream_t stream) {
    const float* x   = (const float*)d_in[0];   // [65536, 64]
    const float* emb = (const float*)d_in[1];   // [64, 2048]
    float* out   = (float*)d_out;
    char*  ws    = (char*)d_ws;
    int*   flags = (int*)(ws + WS_FLAGS_OFF);
    hipLaunchKernelGGL(vq_prep,   dim3(512),         dim3(256), 0, stream, emb, ws, out);
    hipLaunchKernelGGL(vq_main,   dim3(N_ROWS / NB), dim3(256), 0, stream, x, emb, ws, flags, out);
    hipLaunchKernelGGL(vq_refine, dim3(N_ROWS / 32), dim3(256), 0, stream, x, emb, flags, out);
}